// Round 1
// baseline (488.050 us; speedup 1.0000x reference)
//
#include <hip/hip_runtime.h>

typedef __attribute__((ext_vector_type(8))) short short8;
typedef __attribute__((ext_vector_type(8))) unsigned short ushort8;
typedef __attribute__((ext_vector_type(4))) float f32x4;

#define B_   32
#define L_   8192
#define IN_  512
#define HID_ 512
#define D3_  128

static __device__ __forceinline__ short f2bf(float f) {
    return __builtin_bit_cast(short, (__bf16)f);
}
static __device__ __forceinline__ unsigned short f2bfu(float f) {
    return __builtin_bit_cast(unsigned short, (__bf16)f);
}

// ---- prep: Wh (f32, D3 x HID) -> bf16 bits in ws ----
__global__ void prep_whb(const float* __restrict__ wh, unsigned short* __restrict__ whb) {
    int i = (blockIdx.x * 256 + threadIdx.x) * 4;   // 65536 elems / 4
    float4 f = *(const float4*)(wh + i);
    whb[i + 0] = f2bfu(f.x);
    whb[i + 1] = f2bfu(f.y);
    whb[i + 2] = f2bfu(f.z);
    whb[i + 3] = f2bfu(f.w);
}

// ---- prep: qpb[b][d] = inputs[b] . Wi[d] + bi[d] + bh[d]  (fp32) ----
__global__ void prep_qpb(const float* __restrict__ inputs, const float* __restrict__ Wi,
                         const float* __restrict__ bi, const float* __restrict__ bh,
                         float* __restrict__ qpb) {
    int b = blockIdx.x;
    int d = threadIdx.x;                 // 128 threads
    float acc = bi[d] + bh[d];
    const float* xr = inputs + b * IN_;
    const float* wr = Wi + d * IN_;
    #pragma unroll 4
    for (int i = 0; i < IN_; i += 4) {
        float4 x = *(const float4*)(xr + i);
        float4 w = *(const float4*)(wr + i);
        acc += x.x * w.x + x.y * w.y + x.z * w.z + x.w * w.w;
    }
    qpb[b * D3_ + d] = acc;
}

// ---- main: per 128-row tile, k = ctx @ Wh^T (bf16 MFMA), tanh(+qpb), dot V ----
__global__ __launch_bounds__(512, 2) void attn_main(
    const float* __restrict__ ctx, const unsigned short* __restrict__ whb,
    const float* __restrict__ qpb, const float* __restrict__ V,
    float* __restrict__ out)
{
    // All of Wh as bf16, XOR-swizzled: slot s (16B chunks along K) stored at s ^ (col&7)
    __shared__ unsigned short whs[D3_ * HID_];   // 128 KiB

    const int tid = threadIdx.x;

    // stage Wh^bf16 into LDS (once per persistent block)
    #pragma unroll
    for (int p = 0; p < 16; ++p) {
        int m = p * 512 + tid;           // 16B-chunk id: col = m>>6, slot = m&63
        int c = m >> 6;
        int s = m & 63;
        ushort8 v = *(const ushort8*)(whb + (size_t)m * 8);
        *(ushort8*)((char*)whs + c * 1024 + (((s ^ (c & 7)) << 4))) = v;
    }
    __syncthreads();

    const int lane = tid & 63;
    const int w    = tid >> 6;           // wave 0..7, owns 16 rows
    const int cb   = lane & 15;          // col-in-tile / A-row index
    const int g    = lane >> 4;          // k-group 0..3

    float vv[8];
    #pragma unroll
    for (int nt = 0; nt < 8; ++nt) vv[nt] = V[nt * 16 + cb];

    for (int t = 0; t < 8; ++t) {
        const int tile = blockIdx.x * 8 + t;              // 2048 tiles of 128 rows
        const size_t row0 = (size_t)tile * 128 + w * 16;  // this wave's first row
        const int b = (int)(row0 >> 13);                  // row0 / 8192
        const float* arow = ctx + (row0 + cb) * (size_t)HID_ + g * 8;

        float qv[8];
        #pragma unroll
        for (int nt = 0; nt < 8; ++nt) qv[nt] = qpb[b * D3_ + nt * 16 + cb];

        f32x4 acc[8];
        #pragma unroll
        for (int nt = 0; nt < 8; ++nt) acc[nt] = (f32x4){0.f, 0.f, 0.f, 0.f};

        float4 a0 = *(const float4*)(arow);
        float4 a1 = *(const float4*)(arow + 4);

        #pragma unroll
        for (int kk = 0; kk < 16; ++kk) {
            float4 n0, n1;
            if (kk < 15) {                                 // prefetch next K-step
                n0 = *(const float4*)(arow + (kk + 1) * 32);
                n1 = *(const float4*)(arow + (kk + 1) * 32 + 4);
            }
            short8 a8;
            a8[0] = f2bf(a0.x); a8[1] = f2bf(a0.y); a8[2] = f2bf(a0.z); a8[3] = f2bf(a0.w);
            a8[4] = f2bf(a1.x); a8[5] = f2bf(a1.y); a8[6] = f2bf(a1.z); a8[7] = f2bf(a1.w);

            const int s = kk * 4 + g;
            #pragma unroll
            for (int nt = 0; nt < 8; ++nt) {
                const int c = nt * 16 + cb;
                const short8 b8 = *(const short8*)(
                    (const char*)whs + c * 1024 + (((s ^ (c & 7)) << 4)));
                acc[nt] = __builtin_amdgcn_mfma_f32_16x16x32_bf16(a8, b8, acc[nt], 0, 0, 0);
            }
            if (kk < 15) { a0 = n0; a1 = n1; }
        }

        // epilogue: tanh(acc + q) . V, reduce over 128 cols
        float p0 = 0.f, p1 = 0.f, p2 = 0.f, p3 = 0.f;
        #pragma unroll
        for (int nt = 0; nt < 8; ++nt) {
            const float q = qv[nt], vn = vv[nt];
            float x0 = acc[nt][0] + q;
            float x1 = acc[nt][1] + q;
            float x2 = acc[nt][2] + q;
            float x3 = acc[nt][3] + q;
            p0 += (1.f - 2.f / (__expf(2.f * x0) + 1.f)) * vn;
            p1 += (1.f - 2.f / (__expf(2.f * x1) + 1.f)) * vn;
            p2 += (1.f - 2.f / (__expf(2.f * x2) + 1.f)) * vn;
            p3 += (1.f - 2.f / (__expf(2.f * x3) + 1.f)) * vn;
        }
        // reduce across the 16 column-lanes (bits 0..3 of lane)
        #pragma unroll
        for (int m = 1; m < 16; m <<= 1) {
            p0 += __shfl_xor(p0, m, 64);
            p1 += __shfl_xor(p1, m, 64);
            p2 += __shfl_xor(p2, m, 64);
            p3 += __shfl_xor(p3, m, 64);
        }
        if (cb == 0) {
            size_t off = row0 + (size_t)g * 4;   // rows g*4 .. g*4+3 of this wave
            float4 o = make_float4(p0, p1, p2, p3);
            *(float4*)(out + off) = o;
            float4 ones = make_float4(1.f, 1.f, 1.f, 1.f);
            *(float4*)(out + (size_t)B_ * L_ + off) = ones;
        }
    }
}

extern "C" void kernel_launch(void* const* d_in, const int* in_sizes, int n_in,
                              void* d_out, int out_size, void* d_ws, size_t ws_size,
                              hipStream_t stream) {
    const float* inputs  = (const float*)d_in[0];   // (32, 512)
    const float* context = (const float*)d_in[1];   // (32, 8192, 512)
    const float* Wi      = (const float*)d_in[2];   // (128, 512)
    const float* bi      = (const float*)d_in[3];   // (128,)
    const float* Wh      = (const float*)d_in[4];   // (128, 512)
    const float* bh      = (const float*)d_in[5];   // (128,)
    const float* V       = (const float*)d_in[6];   // (128,)
    float* out = (float*)d_out;                     // [att_row 262144][att 262144]

    unsigned short* whb = (unsigned short*)d_ws;                   // 128 KiB
    float* qpb = (float*)((char*)d_ws + (size_t)D3_ * HID_ * 2);   // 16 KiB

    prep_whb<<<64, 256, 0, stream>>>(Wh, whb);
    prep_qpb<<<B_, D3_, 0, stream>>>(inputs, Wi, bi, bh, qpb);
    attn_main<<<256, 512, 0, stream>>>(context, whb, qpb, V, out);
}

// Round 2
// 334.838 us; speedup vs baseline: 1.4576x; 1.4576x over previous
//
#include <hip/hip_runtime.h>

typedef __attribute__((ext_vector_type(8))) short short8;
typedef __attribute__((ext_vector_type(8))) unsigned short ushort8;
typedef __attribute__((ext_vector_type(4))) float f32x4;

#define B_   32
#define L_   8192
#define IN_  512
#define HID_ 512
#define D3_  128

static __device__ __forceinline__ short f2bf(float f) {
    return __builtin_bit_cast(short, (__bf16)f);
}
static __device__ __forceinline__ unsigned short f2bfu(float f) {
    return __builtin_bit_cast(unsigned short, (__bf16)f);
}

// ---- prep: Wh (f32, D3 x HID) -> bf16 bits in ws ----
__global__ void prep_whb(const float* __restrict__ wh, unsigned short* __restrict__ whb) {
    int i = (blockIdx.x * 256 + threadIdx.x) * 4;   // 65536 elems / 4
    float4 f = *(const float4*)(wh + i);
    whb[i + 0] = f2bfu(f.x);
    whb[i + 1] = f2bfu(f.y);
    whb[i + 2] = f2bfu(f.z);
    whb[i + 3] = f2bfu(f.w);
}

// ---- prep: qpb[b][d] = inputs[b] . Wi[d] + bi[d] + bh[d]  (fp32) ----
__global__ void prep_qpb(const float* __restrict__ inputs, const float* __restrict__ Wi,
                         const float* __restrict__ bi, const float* __restrict__ bh,
                         float* __restrict__ qpb) {
    int b = blockIdx.x;
    int d = threadIdx.x;                 // 128 threads
    float acc = bi[d] + bh[d];
    const float* xr = inputs + b * IN_;
    const float* wr = Wi + d * IN_;
    #pragma unroll 4
    for (int i = 0; i < IN_; i += 4) {
        float4 x = *(const float4*)(xr + i);
        float4 w = *(const float4*)(wr + i);
        acc += x.x * w.x + x.y * w.y + x.z * w.z + x.w * w.w;
    }
    qpb[b * D3_ + d] = acc;
}

// ---- main: per 256-row tile, k = ctx @ Wh^T (bf16 MFMA), tanh(+qpb), dot V ----
// 8 waves x 32 rows/wave. Wh^bf16 fully LDS-resident (128 KiB, XOR-swizzled).
// __launch_bounds__(512,1): LDS already pins us to 1 block/CU, so let VGPRs
// float to ~200 -- the (512,2) cap at 128 VGPRs caused 178 MB of spill traffic.
__global__ __launch_bounds__(512, 1) void attn_main(
    const float* __restrict__ ctx, const unsigned short* __restrict__ whb,
    const float* __restrict__ qpb, const float* __restrict__ V,
    float* __restrict__ out)
{
    __shared__ unsigned short whs[D3_ * HID_];   // 128 KiB

    const int tid = threadIdx.x;

    // stage Wh^bf16 into LDS, swizzled: 16B slot s of col c stored at s ^ (c&7)
    #pragma unroll
    for (int p = 0; p < 16; ++p) {
        int m = p * 512 + tid;           // 16B-chunk id: col = m>>6, slot = m&63
        int c = m >> 6;
        int s = m & 63;
        ushort8 v = *(const ushort8*)(whb + (size_t)m * 8);
        *(ushort8*)((char*)whs + c * 1024 + (((s ^ (c & 7)) << 4))) = v;
    }
    __syncthreads();

    const int lane = tid & 63;
    const int w    = tid >> 6;           // wave 0..7, owns 32 rows
    const int cb   = lane & 15;          // M-row (frag) / N-col (output) index
    const int g    = lane >> 4;          // k-group 0..3
    const int sw   = cb & 7;             // swizzle key (col & 7 == cb & 7)
    const char* bbase = (const char*)whs + cb * 1024;

    float vv[8];
    #pragma unroll
    for (int nt = 0; nt < 8; ++nt) vv[nt] = V[nt * 16 + cb];

    for (int t = 0; t < 4; ++t) {
        const int tile = blockIdx.x * 4 + t;              // 1024 tiles of 256 rows
        const size_t row0 = (size_t)tile * 256 + w * 32;  // this wave's first row
        const int b = (int)(row0 >> 13);                  // row0 / 8192
        const float* pA = ctx + (row0 + cb) * (size_t)HID_ + g * 8;   // frag0 row
        const float* pB = pA + 16 * HID_;                             // frag1 row

        float qv[8];
        #pragma unroll
        for (int nt = 0; nt < 8; ++nt) qv[nt] = qpb[b * D3_ + nt * 16 + cb];

        f32x4 acc0[8], acc1[8];
        #pragma unroll
        for (int nt = 0; nt < 8; ++nt) {
            acc0[nt] = (f32x4){0.f, 0.f, 0.f, 0.f};
            acc1[nt] = (f32x4){0.f, 0.f, 0.f, 0.f};
        }

        auto step = [&](float4 a0, float4 a1, float4 b0, float4 b1, int s) {
            short8 aA, aB;
            aA[0] = f2bf(a0.x); aA[1] = f2bf(a0.y); aA[2] = f2bf(a0.z); aA[3] = f2bf(a0.w);
            aA[4] = f2bf(a1.x); aA[5] = f2bf(a1.y); aA[6] = f2bf(a1.z); aA[7] = f2bf(a1.w);
            aB[0] = f2bf(b0.x); aB[1] = f2bf(b0.y); aB[2] = f2bf(b0.z); aB[3] = f2bf(b0.w);
            aB[4] = f2bf(b1.x); aB[5] = f2bf(b1.y); aB[6] = f2bf(b1.z); aB[7] = f2bf(b1.w);
            const char* bp = bbase + ((s ^ sw) << 4);
            #pragma unroll
            for (int nt = 0; nt < 8; ++nt) {
                const short8 bb = *(const short8*)(bp + nt * 16384);
                acc0[nt] = __builtin_amdgcn_mfma_f32_16x16x32_bf16(aA, bb, acc0[nt], 0, 0, 0);
                acc1[nt] = __builtin_amdgcn_mfma_f32_16x16x32_bf16(aB, bb, acc1[nt], 0, 0, 0);
            }
        };

        // 2-deep prefetch, hand-peeled even/odd buffers (all-static indexing)
        float4 P0 = *(const float4*)(pA);           float4 P1 = *(const float4*)(pA + 4);
        float4 P2 = *(const float4*)(pB);           float4 P3 = *(const float4*)(pB + 4);
        float4 Q0 = *(const float4*)(pA + 32);      float4 Q1 = *(const float4*)(pA + 36);
        float4 Q2 = *(const float4*)(pB + 32);      float4 Q3 = *(const float4*)(pB + 36);

        for (int kk = 0; kk < 14; kk += 2) {
            float4 n0 = *(const float4*)(pA + (kk + 2) * 32);
            float4 n1 = *(const float4*)(pA + (kk + 2) * 32 + 4);
            float4 n2 = *(const float4*)(pB + (kk + 2) * 32);
            float4 n3 = *(const float4*)(pB + (kk + 2) * 32 + 4);
            step(P0, P1, P2, P3, kk * 4 + g);
            P0 = n0; P1 = n1; P2 = n2; P3 = n3;

            float4 m0 = *(const float4*)(pA + (kk + 3) * 32);
            float4 m1 = *(const float4*)(pA + (kk + 3) * 32 + 4);
            float4 m2 = *(const float4*)(pB + (kk + 3) * 32);
            float4 m3 = *(const float4*)(pB + (kk + 3) * 32 + 4);
            step(Q0, Q1, Q2, Q3, (kk + 1) * 4 + g);
            Q0 = m0; Q1 = m1; Q2 = m2; Q3 = m3;
        }
        step(P0, P1, P2, P3, 14 * 4 + g);
        step(Q0, Q1, Q2, Q3, 15 * 4 + g);

        // epilogue: tanh(acc + q) . V for both 16-row frags, reduce over n
        float s00 = 0.f, s01 = 0.f, s02 = 0.f, s03 = 0.f;
        float s10 = 0.f, s11 = 0.f, s12 = 0.f, s13 = 0.f;
        #pragma unroll
        for (int nt = 0; nt < 8; ++nt) {
            const float q = qv[nt], vn = vv[nt];
            s00 += (1.f - 2.f / (__expf(2.f * (acc0[nt][0] + q)) + 1.f)) * vn;
            s01 += (1.f - 2.f / (__expf(2.f * (acc0[nt][1] + q)) + 1.f)) * vn;
            s02 += (1.f - 2.f / (__expf(2.f * (acc0[nt][2] + q)) + 1.f)) * vn;
            s03 += (1.f - 2.f / (__expf(2.f * (acc0[nt][3] + q)) + 1.f)) * vn;
            s10 += (1.f - 2.f / (__expf(2.f * (acc1[nt][0] + q)) + 1.f)) * vn;
            s11 += (1.f - 2.f / (__expf(2.f * (acc1[nt][1] + q)) + 1.f)) * vn;
            s12 += (1.f - 2.f / (__expf(2.f * (acc1[nt][2] + q)) + 1.f)) * vn;
            s13 += (1.f - 2.f / (__expf(2.f * (acc1[nt][3] + q)) + 1.f)) * vn;
        }
        #pragma unroll
        for (int m = 1; m < 16; m <<= 1) {
            s00 += __shfl_xor(s00, m, 64); s01 += __shfl_xor(s01, m, 64);
            s02 += __shfl_xor(s02, m, 64); s03 += __shfl_xor(s03, m, 64);
            s10 += __shfl_xor(s10, m, 64); s11 += __shfl_xor(s11, m, 64);
            s12 += __shfl_xor(s12, m, 64); s13 += __shfl_xor(s13, m, 64);
        }
        if (cb == 0) {
            const float4 ones = make_float4(1.f, 1.f, 1.f, 1.f);
            size_t off0 = row0 + (size_t)g * 4;        // frag0 rows
            *(float4*)(out + off0) = make_float4(s00, s01, s02, s03);
            *(float4*)(out + (size_t)B_ * L_ + off0) = ones;
            size_t off1 = off0 + 16;                   // frag1 rows
            *(float4*)(out + off1) = make_float4(s10, s11, s12, s13);
            *(float4*)(out + (size_t)B_ * L_ + off1) = ones;
        }
    }
}

extern "C" void kernel_launch(void* const* d_in, const int* in_sizes, int n_in,
                              void* d_out, int out_size, void* d_ws, size_t ws_size,
                              hipStream_t stream) {
    const float* inputs  = (const float*)d_in[0];   // (32, 512)
    const float* context = (const float*)d_in[1];   // (32, 8192, 512)
    const float* Wi      = (const float*)d_in[2];   // (128, 512)
    const float* bi      = (const float*)d_in[3];   // (128,)
    const float* Wh      = (const float*)d_in[4];   // (128, 512)
    const float* bh      = (const float*)d_in[5];   // (128,)
    const float* V       = (const float*)d_in[6];   // (128,)
    float* out = (float*)d_out;                     // [att_row 262144][att 262144]

    unsigned short* whb = (unsigned short*)d_ws;                   // 128 KiB
    float* qpb = (float*)((char*)d_ws + (size_t)D3_ * HID_ * 2);   // 16 KiB

    prep_whb<<<64, 256, 0, stream>>>(Wh, whb);
    prep_qpb<<<B_, D3_, 0, stream>>>(inputs, Wi, bi, bh, qpb);
    attn_main<<<256, 512, 0, stream>>>(context, whb, qpb, V, out);
}

// Round 3
// 177.744 us; speedup vs baseline: 2.7458x; 1.8838x over previous
//
#include <hip/hip_runtime.h>

typedef __attribute__((ext_vector_type(8))) short short8;
typedef __attribute__((ext_vector_type(8))) unsigned short ushort8;
typedef __attribute__((ext_vector_type(4))) float f32x4;

#define B_   32
#define L_   8192
#define IN_  512
#define HID_ 512
#define D3_  128

static __device__ __forceinline__ short f2bf(float f) {
    return __builtin_bit_cast(short, (__bf16)f);
}
static __device__ __forceinline__ unsigned short f2bfu(float f) {
    return __builtin_bit_cast(unsigned short, (__bf16)f);
}

// ---- prep: Wh (f32, D3 x HID) -> bf16 bits in ws ----
__global__ void prep_whb(const float* __restrict__ wh, unsigned short* __restrict__ whb) {
    int i = (blockIdx.x * 256 + threadIdx.x) * 4;   // 65536 elems / 4
    float4 f = *(const float4*)(wh + i);
    whb[i + 0] = f2bfu(f.x);
    whb[i + 1] = f2bfu(f.y);
    whb[i + 2] = f2bfu(f.z);
    whb[i + 3] = f2bfu(f.w);
}

// ---- prep: qpb[b][d] = inputs[b] . Wi[d] + bi[d] + bh[d]  (fp32) ----
__global__ void prep_qpb(const float* __restrict__ inputs, const float* __restrict__ Wi,
                         const float* __restrict__ bi, const float* __restrict__ bh,
                         float* __restrict__ qpb) {
    int b = blockIdx.x;
    int d = threadIdx.x;                 // 128 threads
    float acc = bi[d] + bh[d];
    const float* xr = inputs + b * IN_;
    const float* wr = Wi + d * IN_;
    #pragma unroll 4
    for (int i = 0; i < IN_; i += 4) {
        float4 x = *(const float4*)(xr + i);
        float4 w = *(const float4*)(wr + i);
        acc += x.x * w.x + x.y * w.y + x.z * w.z + x.w * w.w;
    }
    qpb[b * D3_ + d] = acc;
}

// ---- main ----
// 8 waves. Wave pair (pr, h): pr = row-group (32 rows), h = d3-column half
// (64 cols). Splitting columns across waves keeps per-thread live state
// ~100 VGPRs (acc 32 + prefetch 32) so the empirical 128-VGPR cap causes NO
// spill (R1/R2 spilled 180-212 MB of scratch). Partial V-dot sums from the
// two column halves are combined via a 1 KiB LDS psum buffer per 128-row tile.
__global__ __launch_bounds__(512) void attn_main(
    const float* __restrict__ ctx, const unsigned short* __restrict__ whb,
    const float* __restrict__ qpb, const float* __restrict__ V,
    float* __restrict__ out)
{
    __shared__ unsigned short whs[D3_ * HID_];   // 128 KiB
    __shared__ float psum[2][128];               // 1 KiB

    const int tid = threadIdx.x;

    // stage Wh^bf16 into LDS, swizzled: 16B slot s of col c stored at s ^ (c&7)
    #pragma unroll
    for (int p = 0; p < 16; ++p) {
        int m = p * 512 + tid;           // 16B-chunk id: col = m>>6, slot = m&63
        int c = m >> 6;
        int s = m & 63;
        ushort8 v = *(const ushort8*)(whb + (size_t)m * 8);
        *(ushort8*)((char*)whs + c * 1024 + (((s ^ (c & 7)) << 4))) = v;
    }
    __syncthreads();

    const int lane = tid & 63;
    const int w    = tid >> 6;           // wave 0..7
    const int pr   = w & 3;              // row-group within tile (32 rows)
    const int h    = w >> 2;             // d3-column half (0: cols 0-63, 1: 64-127)
    const int cb   = lane & 15;
    const int g    = lane >> 4;
    const int sw   = cb & 7;             // swizzle key (col&7 == cb&7)
    const char* bbase = (const char*)whs + (h * 64 + cb) * 1024;

    float vv[4];
    #pragma unroll
    for (int nt = 0; nt < 4; ++nt) vv[nt] = V[h * 64 + nt * 16 + cb];

    for (int t = 0; t < 8; ++t) {
        const int tile = blockIdx.x * 8 + t;              // 2048 tiles of 128 rows
        const size_t row0 = (size_t)tile * 128 + pr * 32; // wave-pair's first row
        const int b = (int)(row0 >> 13);
        const float* pA = ctx + (row0 + cb) * (size_t)HID_ + g * 8;   // frag0 row
        const float* pB = pA + 16 * HID_;                             // frag1 row

        float qv[4];
        #pragma unroll
        for (int nt = 0; nt < 4; ++nt) qv[nt] = qpb[b * D3_ + h * 64 + nt * 16 + cb];

        f32x4 acc0[4], acc1[4];
        #pragma unroll
        for (int nt = 0; nt < 4; ++nt) {
            acc0[nt] = (f32x4){0.f, 0.f, 0.f, 0.f};
            acc1[nt] = (f32x4){0.f, 0.f, 0.f, 0.f};
        }

        float4 C0 = *(const float4*)(pA);
        float4 C1 = *(const float4*)(pA + 4);
        float4 C2 = *(const float4*)(pB);
        float4 C3 = *(const float4*)(pB + 4);

        #pragma unroll 2
        for (int kk = 0; kk < 16; ++kk) {
            float4 N0, N1, N2, N3;
            if (kk < 15) {                                 // prefetch next K-step
                N0 = *(const float4*)(pA + (kk + 1) * 32);
                N1 = *(const float4*)(pA + (kk + 1) * 32 + 4);
                N2 = *(const float4*)(pB + (kk + 1) * 32);
                N3 = *(const float4*)(pB + (kk + 1) * 32 + 4);
            }
            short8 aA, aB;
            aA[0] = f2bf(C0.x); aA[1] = f2bf(C0.y); aA[2] = f2bf(C0.z); aA[3] = f2bf(C0.w);
            aA[4] = f2bf(C1.x); aA[5] = f2bf(C1.y); aA[6] = f2bf(C1.z); aA[7] = f2bf(C1.w);
            aB[0] = f2bf(C2.x); aB[1] = f2bf(C2.y); aB[2] = f2bf(C2.z); aB[3] = f2bf(C2.w);
            aB[4] = f2bf(C3.x); aB[5] = f2bf(C3.y); aB[6] = f2bf(C3.z); aB[7] = f2bf(C3.w);

            const int off = (((kk * 4 + g) ^ sw) << 4);
            #pragma unroll
            for (int nt = 0; nt < 4; ++nt) {
                const short8 bb = *(const short8*)(bbase + nt * 16384 + off);
                acc0[nt] = __builtin_amdgcn_mfma_f32_16x16x32_bf16(aA, bb, acc0[nt], 0, 0, 0);
                acc1[nt] = __builtin_amdgcn_mfma_f32_16x16x32_bf16(aB, bb, acc1[nt], 0, 0, 0);
            }
            if (kk < 15) { C0 = N0; C1 = N1; C2 = N2; C3 = N3; }
        }

        // epilogue: tanh(acc + q) . V (this wave's 64-col partial), reduce over cb
        float s00 = 0.f, s01 = 0.f, s02 = 0.f, s03 = 0.f;
        float s10 = 0.f, s11 = 0.f, s12 = 0.f, s13 = 0.f;
        #pragma unroll
        for (int nt = 0; nt < 4; ++nt) {
            const float q = qv[nt], vn = vv[nt];
            s00 += (1.f - 2.f / (__expf(2.f * (acc0[nt][0] + q)) + 1.f)) * vn;
            s01 += (1.f - 2.f / (__expf(2.f * (acc0[nt][1] + q)) + 1.f)) * vn;
            s02 += (1.f - 2.f / (__expf(2.f * (acc0[nt][2] + q)) + 1.f)) * vn;
            s03 += (1.f - 2.f / (__expf(2.f * (acc0[nt][3] + q)) + 1.f)) * vn;
            s10 += (1.f - 2.f / (__expf(2.f * (acc1[nt][0] + q)) + 1.f)) * vn;
            s11 += (1.f - 2.f / (__expf(2.f * (acc1[nt][1] + q)) + 1.f)) * vn;
            s12 += (1.f - 2.f / (__expf(2.f * (acc1[nt][2] + q)) + 1.f)) * vn;
            s13 += (1.f - 2.f / (__expf(2.f * (acc1[nt][3] + q)) + 1.f)) * vn;
        }
        #pragma unroll
        for (int m = 1; m < 16; m <<= 1) {
            s00 += __shfl_xor(s00, m, 64); s01 += __shfl_xor(s01, m, 64);
            s02 += __shfl_xor(s02, m, 64); s03 += __shfl_xor(s03, m, 64);
            s10 += __shfl_xor(s10, m, 64); s11 += __shfl_xor(s11, m, 64);
            s12 += __shfl_xor(s12, m, 64); s13 += __shfl_xor(s13, m, 64);
        }
        if (cb == 0) {
            const int r0 = pr * 32 + g * 4;     // frag0 rows within tile
            psum[h][r0 + 0] = s00; psum[h][r0 + 1] = s01;
            psum[h][r0 + 2] = s02; psum[h][r0 + 3] = s03;
            psum[h][r0 + 16 + 0] = s10; psum[h][r0 + 16 + 1] = s11;
            psum[h][r0 + 16 + 2] = s12; psum[h][r0 + 16 + 3] = s13;
        }
        __syncthreads();
        if (tid < 128) {
            const size_t row = (size_t)tile * 128 + tid;
            out[row] = psum[0][tid] + psum[1][tid];
            out[(size_t)B_ * L_ + row] = 1.0f;
        }
        __syncthreads();
    }
}

extern "C" void kernel_launch(void* const* d_in, const int* in_sizes, int n_in,
                              void* d_out, int out_size, void* d_ws, size_t ws_size,
                              hipStream_t stream) {
    const float* inputs  = (const float*)d_in[0];   // (32, 512)
    const float* context = (const float*)d_in[1];   // (32, 8192, 512)
    const float* Wi      = (const float*)d_in[2];   // (128, 512)
    const float* bi      = (const float*)d_in[3];   // (128,)
    const float* Wh      = (const float*)d_in[4];   // (128, 512)
    const float* bh      = (const float*)d_in[5];   // (128,)
    const float* V       = (const float*)d_in[6];   // (128,)
    float* out = (float*)d_out;                     // [att_row 262144][att 262144]

    unsigned short* whb = (unsigned short*)d_ws;                   // 128 KiB
    float* qpb = (float*)((char*)d_ws + (size_t)D3_ * HID_ * 2);   // 16 KiB

    prep_whb<<<64, 256, 0, stream>>>(Wh, whb);
    prep_qpb<<<B_, D3_, 0, stream>>>(inputs, Wi, bi, bh, qpb);
    attn_main<<<256, 512, 0, stream>>>(context, whb, qpb, V, out);
}